// Round 4
// baseline (491.721 us; speedup 1.0000x reference)
//
#include <hip/hip_runtime.h>
#include <hip/hip_bf16.h>

#define NN 512
#define MM (NN*NN)   // 262144 rows

typedef __attribute__((ext_vector_type(8))) unsigned short u16x8;
typedef __attribute__((ext_vector_type(4))) unsigned short u16x4;
typedef __attribute__((ext_vector_type(8))) __bf16 bf16x8;
typedef __attribute__((ext_vector_type(4))) float f32x4;

static __device__ __forceinline__ unsigned short f2bfi(float f) {
  return __builtin_bit_cast(unsigned short, __float2bfloat16(f));
}
static __device__ __forceinline__ float bf2f(unsigned short h) {
  return __uint_as_float(((unsigned int)h) << 16);
}
static __device__ __forceinline__ bf16x8 ldfrag(const unsigned short* p) {
  u16x8 v = *(const u16x8*)p;
  return __builtin_bit_cast(bf16x8, v);
}
static __device__ __forceinline__ float sigm(float x) {
  return 1.0f / (1.0f + __expf(-x));
}

// ---------------- prep ------------------------------------------------------------------
// WT_lu[n][k] (128x128 bf16) for K3;  WF: fragment-ordered weights for K1's 5 GEMMs:
// WF[gm][w][ks][lane][8j]: col = w*16+(lane&15), k = ks*32+(lane>>4)*8+j, gm in {ga,la,gb,lb,g}
__global__ void prep_weights(const float* __restrict__ ga_w, const float* __restrict__ la_w,
                             const float* __restrict__ gb_w, const float* __restrict__ lb_w,
                             const float* __restrict__ g_w,  const float* __restrict__ lu_w,
                             unsigned short* __restrict__ WT_lu, unsigned short* __restrict__ WF) {
  int idx = blockIdx.x * 256 + threadIdx.x;   // grid 384*256 = 98304 = 16384 + 81920
  if (idx < 16384) {
    int n = idx >> 7, k = idx & 127;
    WT_lu[idx] = f2bfi(lu_w[k * 128 + n]);
  } else {
    int id2 = idx - 16384;
    int j = id2 & 7, lane = (id2 >> 3) & 63, ks = (id2 >> 9) & 3, w = (id2 >> 11) & 7, gm = id2 >> 14;
    int col = w * 16 + (lane & 15);
    int k = ks * 32 + (lane >> 4) * 8 + j;
    const float* tabs[5] = {ga_w, la_w, gb_w, lb_w, g_w};
    WF[id2] = f2bfi(tabs[gm][k * 128 + col]);
  }
}

// ---------------- K1: fused LN + 5 projections, wave-independent -----------------------
// grid.x = M/128, block = 512 (8 waves). Wave w owns output cols [w*16, w*16+16) x 128 rows
// per GEMM. Weights come straight from global WF (L2-hot, coalesced frags); only 3 barriers.
__global__ __launch_bounds__(512, 4) void k1_proj(
    const float* __restrict__ pair, const float* __restrict__ lng, const float* __restrict__ lnb,
    const unsigned short* __restrict__ WF,
    const float* __restrict__ ga_b, const float* __restrict__ la_b,
    const float* __restrict__ gb_b, const float* __restrict__ lb_b,
    const float* __restrict__ g_b,
    unsigned short* __restrict__ a_t, unsigned short* __restrict__ b_t,
    unsigned short* __restrict__ g_buf) {
  __shared__ __align__(16) unsigned short sZ[128 * 136];  // 34816 B (z, later g staging)
  __shared__ __align__(16) unsigned short sS[8 * 1088];   // 17408 B (per-wave 16x68 epi stage)
  const int t = threadIdx.x;
  const size_t m0 = (size_t)blockIdx.x * 128;
  const int wave = t >> 6, lane = t & 63, lrow = lane & 15, qk = lane >> 4;
  const int w16 = wave * 16;
  const int mycol = w16 + lrow;
  const float bga = ga_b[mycol], bla = la_b[mycol];
  const float bgb = gb_b[mycol], blb = lb_b[mycol];
  const float bgg = g_b[mycol];

  // ---- LN: 128 rows of pair -> sZ (bf16) ----
  {
    const int row = t >> 2, q = t & 3;
    const float* pr = pair + (m0 + row) * 128 + q * 32;
    float vals[32];
    float s = 0.f, ss = 0.f;
#pragma unroll
    for (int it = 0; it < 8; ++it) {
      f32x4 v = *(const f32x4*)(pr + it * 4);
#pragma unroll
      for (int j = 0; j < 4; ++j) { float x = v[j]; vals[it * 4 + j] = x; s += x; ss += x * x; }
    }
    s += __shfl_xor(s, 1);  s += __shfl_xor(s, 2);
    ss += __shfl_xor(ss, 1); ss += __shfl_xor(ss, 2);
    const float mean = s * (1.f / 128.f);
    const float var  = ss * (1.f / 128.f) - mean * mean;
    const float rstd = rsqrtf(var + 1e-5f);
#pragma unroll
    for (int i = 0; i < 4; ++i) {
      u16x8 pk;
#pragma unroll
      for (int j = 0; j < 8; ++j) {
        int c = q * 32 + i * 8 + j;
        pk[j] = f2bfi((vals[i * 8 + j] - mean) * rstd * lng[c] + lnb[c]);
      }
      *(u16x8*)(sZ + row * 136 + q * 32 + i * 8) = pk;
    }
  }
  __syncthreads();                                        // b1: z ready (only barrier until g)

  const unsigned short* zb = sZ + lrow * 136 + qk * 8;    // per-lane z base; rest is immediates
  const unsigned short* wfbase = WF + wave * 2048 + lane * 8;
  f32x4 accg[8], accl[8];

  // paired GEMMs: one z-fragment read feeds both weight matrices
  auto pair_pass = [&](const unsigned short* wf1, const unsigned short* wf2) {
#pragma unroll
    for (int m = 0; m < 8; ++m)
#pragma unroll
      for (int r = 0; r < 4; ++r) { accg[m][r] = 0.f; accl[m][r] = 0.f; }
#pragma unroll
    for (int ks = 0; ks < 4; ++ks) {
      bf16x8 b1 = ldfrag(wf1 + ks * 512);
      bf16x8 b2 = ldfrag(wf2 + ks * 512);
#pragma unroll
      for (int m = 0; m < 8; ++m) {
        bf16x8 av = ldfrag(zb + m * 2176 + ks * 32);
        accg[m] = __builtin_amdgcn_mfma_f32_16x16x32_bf16(av, b1, accg[m], 0, 0, 0);
        accl[m] = __builtin_amdgcn_mfma_f32_16x16x32_bf16(av, b2, accl[m], 0, 0, 0);
      }
    }
  };

  // per-wave epilogue: sigmoid-gate, transpose via own LDS scratch, 128B-run global stores
  auto epi_ab = [&](unsigned short* dst, float bg, float bl) {
    unsigned short* st = sS + wave * 1088;
#pragma unroll
    for (int half = 0; half < 2; ++half) {
#pragma unroll
      for (int mm = 0; mm < 4; ++mm) {
        int m = half * 4 + mm;
        u16x4 pk;
#pragma unroll
        for (int r = 0; r < 4; ++r)
          pk[r] = f2bfi(sigm(accg[m][r] + bg) * (accl[m][r] + bl));
        *(u16x4*)(st + lrow * 68 + mm * 16 + qk * 4) = pk;
      }
      int c4 = lane >> 2, rq = lane & 3;
      u16x8 v0 = *(const u16x8*)(st + c4 * 68 + rq * 16);
      u16x8 v1 = *(const u16x8*)(st + c4 * 68 + rq * 16 + 8);
      unsigned short* dp = dst + (size_t)(w16 + c4) * MM + m0 + half * 64 + rq * 16;
      *(u16x8*)dp = v0;
      *(u16x8*)(dp + 8) = v1;
    }
  };

  pair_pass(wfbase, wfbase + 16384);                      // ga, la
  epi_ab(a_t, bga, bla);
  pair_pass(wfbase + 2 * 16384, wfbase + 3 * 16384);      // gb, lb
  epi_ab(b_t, bgb, blb);

  // g GEMM into accg
  {
    const unsigned short* wf = wfbase + 4 * 16384;
#pragma unroll
    for (int m = 0; m < 8; ++m)
#pragma unroll
      for (int r = 0; r < 4; ++r) accg[m][r] = 0.f;
#pragma unroll
    for (int ks = 0; ks < 4; ++ks) {
      bf16x8 b1 = ldfrag(wf + ks * 512);
#pragma unroll
      for (int m = 0; m < 8; ++m) {
        bf16x8 av = ldfrag(zb + m * 2176 + ks * 32);
        accg[m] = __builtin_amdgcn_mfma_f32_16x16x32_bf16(av, b1, accg[m], 0, 0, 0);
      }
    }
  }
  __syncthreads();                                        // b2: all z reads done, sZ reusable
#pragma unroll
  for (int m = 0; m < 8; ++m)
#pragma unroll
    for (int r = 0; r < 4; ++r)
      sZ[(m * 16 + qk * 4 + r) * 136 + mycol] = f2bfi(sigm(accg[m][r] + bgg));
  __syncthreads();                                        // b3
#pragma unroll
  for (int it = 0; it < 4; ++it) {
    int idx = it * 512 + t;
    int mr = idx >> 4, off = (idx & 15) * 8;
    *(u16x8*)(g_buf + (m0 + mr) * 128 + off) = *(const u16x8*)(sZ + mr * 136 + off);
  }
}

// ---------------- K2: channel-batched NT GEMM update_t[c] = A_c * B_c^T ----------------
// 1-D grid 2048 = 128 channels x 16 tiles, XCD-chunk swizzled; double-buffered k-loop.
__global__ __launch_bounds__(256) void k2_einsum(
    const unsigned short* __restrict__ a_t, const unsigned short* __restrict__ b_t,
    unsigned short* __restrict__ up_t) {
  __shared__ __align__(16) unsigned short sA[2][128 * 40];
  __shared__ __align__(16) unsigned short sB[2][128 * 40];
  const int t = threadIdx.x;
  const int wid = (blockIdx.x & 7) * 256 + (blockIdx.x >> 3);
  const int c = wid >> 4;
  const int i0 = ((wid >> 2) & 3) * 128, j0 = (wid & 3) * 128;
  const unsigned short* Ag = a_t + (size_t)c * MM + (size_t)i0 * 512;
  const unsigned short* Bg = b_t + (size_t)c * MM + (size_t)j0 * 512;
  const int wave = t >> 6, lane = t & 63, wr = wave >> 1, wc = wave & 1;
  const int lrow = lane & 15, qk = lane >> 4;
  const int srow = t >> 2, sq = t & 3;
  f32x4 acc[4][4];
#pragma unroll
  for (int i = 0; i < 4; ++i)
#pragma unroll
    for (int j = 0; j < 4; ++j)
#pragma unroll
      for (int r = 0; r < 4; ++r) acc[i][j][r] = 0.f;

  u16x8 ra[2], rb[2];
  auto tile_ld = [&](int k0) {
#pragma unroll
    for (int h = 0; h < 2; ++h) {
      int row = h * 64 + srow;
      ra[h] = *(const u16x8*)(Ag + (size_t)row * 512 + k0 + sq * 8);
      rb[h] = *(const u16x8*)(Bg + (size_t)row * 512 + k0 + sq * 8);
    }
  };
  auto tile_st = [&](int buf) {
#pragma unroll
    for (int h = 0; h < 2; ++h) {
      int row = h * 64 + srow;
      *(u16x8*)(sA[buf] + row * 40 + sq * 8) = ra[h];
      *(u16x8*)(sB[buf] + row * 40 + sq * 8) = rb[h];
    }
  };

  tile_ld(0);
  tile_st(0);
  __syncthreads();
  int cur = 0;
  for (int ks = 0; ks < 16; ++ks) {
    if (ks < 15) tile_ld((ks + 1) * 32);
    bf16x8 afr[4], bv[4];
#pragma unroll
    for (int mt = 0; mt < 4; ++mt)
      afr[mt] = ldfrag(sA[cur] + (wr * 64 + mt * 16 + lrow) * 40 + 8 * qk);
#pragma unroll
    for (int nt = 0; nt < 4; ++nt)
      bv[nt] = ldfrag(sB[cur] + (wc * 64 + nt * 16 + lrow) * 40 + 8 * qk);
#pragma unroll
    for (int mt = 0; mt < 4; ++mt)
#pragma unroll
      for (int nt = 0; nt < 4; ++nt)
        acc[mt][nt] = __builtin_amdgcn_mfma_f32_16x16x32_bf16(afr[mt], bv[nt], acc[mt][nt], 0, 0, 0);
    if (ks < 15) tile_st(cur ^ 1);
    __syncthreads();
    cur ^= 1;
  }
  unsigned short* up = up_t + (size_t)c * MM;
#pragma unroll
  for (int mt = 0; mt < 4; ++mt)
#pragma unroll
    for (int nt = 0; nt < 4; ++nt) {
      int col = j0 + wc * 64 + nt * 16 + lrow;
#pragma unroll
      for (int r = 0; r < 4; ++r) {
        int row = i0 + wr * 64 + mt * 16 + qk * 4 + r;
        up[(size_t)row * 512 + col] = f2bfi(acc[mt][nt][r]);
      }
    }
}

// ---------------- K3: LN(update) @ lu_w + lu_b, * g -> out -----------------------------
// grid.x = M/64
__global__ __launch_bounds__(256) void k3_final(
    const unsigned short* __restrict__ up_t, const unsigned short* __restrict__ g_buf,
    const unsigned short* __restrict__ WT_lu,
    const float* __restrict__ lnug, const float* __restrict__ lnub,
    const float* __restrict__ lu_b, float* __restrict__ out) {
  __shared__ __align__(16) unsigned short sU[64 * 138];
  __shared__ __align__(16) unsigned short sA[64 * 136];
  __shared__ __align__(16) unsigned short sB[128 * 136];
  const int t = threadIdx.x;
  const size_t m0 = (size_t)blockIdx.x * 64;
#pragma unroll
  for (int it = 0; it < 4; ++it) {
    int idx = it * 256 + t;
    int c = idx >> 3, m8 = (idx & 7) * 8;
    u16x8 v = *(const u16x8*)(up_t + (size_t)c * MM + m0 + m8);
#pragma unroll
    for (int j = 0; j < 8; ++j) sU[(m8 + j) * 138 + c] = v[j];
  }
#pragma unroll
  for (int it = 0; it < 8; ++it) {
    int idx = it * 256 + t;
    int n = idx >> 4, off = (idx & 15) * 8;
    *(u16x8*)(sB + n * 136 + off) = *(const u16x8*)(WT_lu + (size_t)n * 128 + off);
  }
  __syncthreads();
  {
    const int row = t >> 2, q = t & 3;
    float vals[32]; float s = 0.f, ss = 0.f;
#pragma unroll
    for (int jj = 0; jj < 32; ++jj) {
      int cc = q + jj * 4;
      float x = bf2f(sU[row * 138 + cc]);
      vals[jj] = x; s += x; ss += x * x;
    }
    s += __shfl_xor(s, 1);  s += __shfl_xor(s, 2);
    ss += __shfl_xor(ss, 1); ss += __shfl_xor(ss, 2);
    float mean = s * (1.f / 128.f);
    float var  = ss * (1.f / 128.f) - mean * mean;
    float rstd = rsqrtf(var + 1e-5f);
#pragma unroll
    for (int jj = 0; jj < 32; ++jj) {
      int cc = q + jj * 4;
      float zn = (vals[jj] - mean) * rstd * lnug[cc] + lnub[cc];
      sA[row * 136 + cc] = f2bfi(zn);
    }
  }
  __syncthreads();
  const int wave = t >> 6, lane = t & 63, lrow = lane & 15, qk = lane >> 4;
  f32x4 acc[8];
#pragma unroll
  for (int i = 0; i < 8; ++i)
#pragma unroll
    for (int r = 0; r < 4; ++r) acc[i][r] = 0.f;
#pragma unroll
  for (int ks = 0; ks < 4; ++ks) {
    int k0 = ks * 32;
    bf16x8 af = ldfrag(sA + (wave * 16 + lrow) * 136 + k0 + 8 * qk);
#pragma unroll
    for (int nt = 0; nt < 8; ++nt) {
      bf16x8 bv = ldfrag(sB + (nt * 16 + lrow) * 136 + k0 + 8 * qk);
      acc[nt] = __builtin_amdgcn_mfma_f32_16x16x32_bf16(af, bv, acc[nt], 0, 0, 0);
    }
  }
#pragma unroll
  for (int nt = 0; nt < 8; ++nt) {
    int e = nt * 16 + lrow;
    float bb = lu_b[e];
#pragma unroll
    for (int r = 0; r < 4; ++r) {
      size_t m = m0 + wave * 16 + qk * 4 + r;
      float lin = acc[nt][r] + bb;
      float gv = bf2f(g_buf[m * 128 + e]);
      out[m * 128 + e] = gv * lin;
    }
  }
}

extern "C" void kernel_launch(void* const* d_in, const int* in_sizes, int n_in,
                              void* d_out, int out_size, void* d_ws, size_t ws_size,
                              hipStream_t stream) {
  const float* pair = (const float*)d_in[0];
  const float* lng  = (const float*)d_in[1];
  const float* lnb  = (const float*)d_in[2];
  const float* ga_w = (const float*)d_in[3];
  const float* ga_b = (const float*)d_in[4];
  const float* la_w = (const float*)d_in[5];
  const float* la_b = (const float*)d_in[6];
  const float* gb_w = (const float*)d_in[7];
  const float* gb_b = (const float*)d_in[8];
  const float* lb_w = (const float*)d_in[9];
  const float* lb_b = (const float*)d_in[10];
  const float* g_w  = (const float*)d_in[11];
  const float* g_b  = (const float*)d_in[12];
  const float* lnug = (const float*)d_in[13];
  const float* lnub = (const float*)d_in[14];
  const float* lu_w = (const float*)d_in[15];
  const float* lu_b = (const float*)d_in[16];
  float* out = (float*)d_out;

  char* ws = (char*)d_ws;
  unsigned short* WT_lu = (unsigned short*)(ws);                   // 128*128*2 = 32768 B
  unsigned short* WF    = (unsigned short*)(ws + 32768ull);        // 5*8*4*64*8*2 = 327680 B
  unsigned short* a_t   = (unsigned short*)(ws + 360448ull);       // 128*M*2 = 67108864 B
  unsigned short* b_t   = (unsigned short*)(ws + 67469312ull);     // 128*M*2
  unsigned short* g_buf = (unsigned short*)(ws + 134578176ull);    // M*128*2
  unsigned short* up_t  = (unsigned short*)(ws + 201687040ull);    // 128*M*2 (end ~268.8 MB)

  hipLaunchKernelGGL(prep_weights, dim3(384), dim3(256), 0, stream,
                     ga_w, la_w, gb_w, lb_w, g_w, lu_w, WT_lu, WF);
  hipLaunchKernelGGL(k1_proj, dim3(2048), dim3(512), 0, stream,
                     pair, lng, lnb, WF, ga_b, la_b, gb_b, lb_b, g_b, a_t, b_t, g_buf);
  hipLaunchKernelGGL(k2_einsum, dim3(2048), dim3(256), 0, stream, a_t, b_t, up_t);
  hipLaunchKernelGGL(k3_final, dim3(4096), dim3(256), 0, stream,
                     up_t, g_buf, WT_lu, lnug, lnub, lu_b, out);
}